// Round 2
// baseline (650.260 us; speedup 1.0000x reference)
//
#include <hip/hip_runtime.h>
#include <stdint.h>

typedef unsigned short u16;
typedef __bf16 bf16x8 __attribute__((ext_vector_type(8)));
typedef float f32x4 __attribute__((ext_vector_type(4)));
typedef u16 u16x8 __attribute__((ext_vector_type(8)));

// ---------- helpers ----------
__device__ __forceinline__ u16 bf16_bits(float f) {
  uint32_t x = __float_as_uint(f);
  uint32_t r = (x + 0x7FFFu + ((x >> 16) & 1u)) >> 16;
  return (u16)r;
}
__device__ __forceinline__ float bits_f32(u16 u) {
  return __uint_as_float(((uint32_t)u) << 16);
}
__device__ __forceinline__ float sigm(float x) { return 1.f / (1.f + expf(-x)); }

__device__ __forceinline__ void gload_lds16(const void* g, void* l) {
  // async global->LDS, 16B/lane; LDS dest = wave-uniform base + lane*16
  __builtin_amdgcn_global_load_lds(
      (const __attribute__((address_space(1))) void*)g,
      (__attribute__((address_space(3))) void*)l,
      16, 0, 0);
}

// ---------- conversion kernels ----------
__global__ __launch_bounds__(256) void cvt_bf16_kernel(const float* __restrict__ src,
                                                       u16* __restrict__ dst, int n8) {
  int i = blockIdx.x * 256 + threadIdx.x;
  if (i >= n8) return;
  const f32x4* s = (const f32x4*)(src + (size_t)i * 8);
  f32x4 a = s[0], b = s[1];
  u16x8 o;
#pragma unroll
  for (int k = 0; k < 4; ++k) { o[k] = bf16_bits(a[k]); o[4 + k] = bf16_bits(b[k]); }
  *(u16x8*)(dst + (size_t)i * 8) = o;
}

// h_tm1 (2048x1024 f32) -> XH_B columns [2048..3071] (ld 3072)
__global__ __launch_bounds__(256) void cvt_h_kernel(const float* __restrict__ src,
                                                    u16* __restrict__ xh) {
  int i = blockIdx.x * 256 + threadIdx.x;  // 0..262143
  int row = i >> 7;
  int c0 = (i & 127) << 3;
  const f32x4* s = (const f32x4*)(src + (size_t)row * 1024 + c0);
  f32x4 a = s[0], b = s[1];
  u16x8 o;
#pragma unroll
  for (int k = 0; k < 4; ++k) { o[k] = bf16_bits(a[k]); o[4 + k] = bf16_bits(b[k]); }
  *(u16x8*)(xh + (size_t)row * 3072 + 2048 + c0) = o;
}

// src (K x N f32, row-major) -> dst[dstOff + n*dstLd + k] = bf16(src[k][n])
__global__ __launch_bounds__(256) void transpose_cvt(const float* __restrict__ src, int K, int N,
                                                     u16* __restrict__ dst, int dstLd,
                                                     long long dstOff) {
  __shared__ float t[32][33];
  int n0 = blockIdx.x * 32, k0 = blockIdx.y * 32;
  int tx = threadIdx.x & 31, ty = threadIdx.x >> 5;  // 32 x 8
#pragma unroll
  for (int r = ty; r < 32; r += 8) t[r][tx] = src[(size_t)(k0 + r) * N + n0 + tx];
  __syncthreads();
#pragma unroll
  for (int r = ty; r < 32; r += 8)
    dst[dstOff + (size_t)(n0 + r) * dstLd + k0 + tx] = bf16_bits(t[tx][r]);
}

// ---------- GEMM: C(MxN) = A(MxK,bf16) * Bt(NxK,bf16)^T, fp32 accum ----------
enum { EPI_F32 = 0, EPI_BF16 = 1, EPI_DEC = 2, EPI_TANH = 3 };

template <int EPI>
__global__ __launch_bounds__(256) void gemm_bt(
    const u16* __restrict__ A, int lda, const u16* __restrict__ Bt, int M, int N, int K,
    float* __restrict__ C, int ldc, u16* __restrict__ Cb, int ldcb,
    const float* __restrict__ bias, const float* __restrict__ aux1,
    const float* __restrict__ aux2) {
  __shared__ u16 As[128 * 32];
  __shared__ u16 Bs[128 * 32];
  const int tid = threadIdx.x;
  const int lane = tid & 63;
  const int wid = tid >> 6;
  const int wr = wid >> 1, wc = wid & 1;
  const int brow = blockIdx.y * 128;
  const int bcol = blockIdx.x * 128;

  f32x4 acc[4][4] = {};

  const int s0 = wid, s1 = wid + 4;          // 1KB segments this wave stages
  const int oA0 = s0 * 1024 + lane * 16;     // linear byte offset in 8KB tile
  const int oA1 = s1 * 1024 + lane * 16;

  const int nk = K >> 5;
  for (int kt = 0; kt < nk; ++kt) {
    __syncthreads();
    {
      const char* g;
      int o = oA0;
      g = (const char*)A + (((size_t)(brow + (o >> 6)) * lda) << 1) + (kt << 6) + (o & 63);
      gload_lds16(g, (char*)As + s0 * 1024);
      o = oA1;
      g = (const char*)A + (((size_t)(brow + (o >> 6)) * lda) << 1) + (kt << 6) + (o & 63);
      gload_lds16(g, (char*)As + s1 * 1024);
      o = oA0;
      g = (const char*)Bt + (((size_t)(bcol + (o >> 6)) * K) << 1) + (kt << 6) + (o & 63);
      gload_lds16(g, (char*)Bs + s0 * 1024);
      o = oA1;
      g = (const char*)Bt + (((size_t)(bcol + (o >> 6)) * K) << 1) + (kt << 6) + (o & 63);
      gload_lds16(g, (char*)Bs + s1 * 1024);
    }
    __syncthreads();

    bf16x8 af[4], bf[4];
#pragma unroll
    for (int m = 0; m < 4; ++m) {
      int r = wr * 64 + m * 16 + (lane & 15);
      af[m] = *(const bf16x8*)((const char*)As + r * 64 + ((lane >> 4) << 4));
    }
#pragma unroll
    for (int n = 0; n < 4; ++n) {
      int cidx = wc * 64 + n * 16 + (lane & 15);
      bf[n] = *(const bf16x8*)((const char*)Bs + cidx * 64 + ((lane >> 4) << 4));
    }
#pragma unroll
    for (int m = 0; m < 4; ++m)
#pragma unroll
      for (int n = 0; n < 4; ++n)
        acc[m][n] = __builtin_amdgcn_mfma_f32_16x16x32_bf16(af[m], bf[n], acc[m][n], 0, 0, 0);
  }

  const int r0 = brow + wr * 64 + ((lane >> 4) << 2);
  const int c0 = bcol + wc * 64 + (lane & 15);
#pragma unroll
  for (int m = 0; m < 4; ++m) {
#pragma unroll
    for (int n = 0; n < 4; ++n) {
#pragma unroll
      for (int j = 0; j < 4; ++j) {
        int gr = r0 + m * 16 + j;
        int gc = c0 + n * 16;
        float v = acc[m][n][j];
        size_t ci = (size_t)gr * ldc + gc;
        if constexpr (EPI == EPI_F32) {
          C[ci] = v;
        } else if constexpr (EPI == EPI_BF16) {
          Cb[(size_t)gr * ldcb + gc] = bf16_bits(v);
        } else if constexpr (EPI == EPI_DEC) {
          float pre = v + bias[gc];
          float d = sigm(pre);
          float cro = 0.5f * aux1[ci] * d + 0.5f * aux2[ci];
          C[ci] = cro;
          Cb[(size_t)gr * ldcb + gc] = bf16_bits(cro);
        } else {  // EPI_TANH
          C[ci] = tanhf(v + bias[gc]);
        }
      }
    }
  }
}

// ---------- softmax + x ----------
// T_ALL row layout (ld 4096): [t12 | t21 | v12 | v21], each 1024 wide.
// block = (row, half): s = tanh(t)*v over 1024 cols; ca = softmax(s); x = e*ca
__global__ __launch_bounds__(256) void softmax_x_kernel(
    const float* __restrict__ T_ALL, const u16* __restrict__ E_B,
    float* __restrict__ X_F, u16* __restrict__ XH_B) {
  __shared__ float smx[4], sms[4];
  int row = blockIdx.x >> 1;
  int half = blockIdx.x & 1;
  const float* T = T_ALL + (size_t)row * 4096 + half * 1024;         // t12 / t21
  const float* V = T_ALL + (size_t)row * 4096 + 2048 + half * 1024;  // v12 / v21
  int tid = threadIdx.x;
  float s[4];
  float lmax = -1e30f;
#pragma unroll
  for (int i = 0; i < 4; ++i) {
    int c = tid + (i << 8);
    s[i] = tanhf(T[c]) * V[c];
    lmax = fmaxf(lmax, s[i]);
  }
#pragma unroll
  for (int o = 32; o; o >>= 1) lmax = fmaxf(lmax, __shfl_xor(lmax, o, 64));
  if ((tid & 63) == 0) smx[tid >> 6] = lmax;
  __syncthreads();
  float bmax = fmaxf(fmaxf(smx[0], smx[1]), fmaxf(smx[2], smx[3]));
  float lsum = 0.f;
#pragma unroll
  for (int i = 0; i < 4; ++i) { s[i] = expf(s[i] - bmax); lsum += s[i]; }
#pragma unroll
  for (int o = 32; o; o >>= 1) lsum += __shfl_xor(lsum, o, 64);
  if ((tid & 63) == 0) sms[tid >> 6] = lsum;
  __syncthreads();
  float inv = 1.f / (sms[0] + sms[1] + sms[2] + sms[3]);
#pragma unroll
  for (int i = 0; i < 4; ++i) {
    int c = tid + (i << 8);
    size_t ei = (size_t)row * 2048 + half * 1024 + c;
    float x = bits_f32(E_B[ei]) * s[i] * inv;
    X_F[ei] = x;
    XH_B[(size_t)row * 3072 + half * 1024 + c] = bf16_bits(x);
  }
}

// ---------- LSTM gates ----------
__global__ __launch_bounds__(256) void gates_kernel(
    const float* __restrict__ Z, const float* __restrict__ bias,
    const float* __restrict__ c_tm1, const float* __restrict__ hcro,
    float* __restrict__ out_h, float* __restrict__ out_c) {
  int i = blockIdx.x * 256 + threadIdx.x;  // 0..524287, 4 units each
  int row = i >> 8;
  int u0 = (i & 255) << 2;
  const float* zr = Z + (size_t)row * 4096;
  f32x4 zi = *(const f32x4*)(zr + u0);
  f32x4 zf = *(const f32x4*)(zr + 1024 + u0);
  f32x4 zc = *(const f32x4*)(zr + 2048 + u0);
  f32x4 zo = *(const f32x4*)(zr + 3072 + u0);
  f32x4 bi = *(const f32x4*)(bias + u0);
  f32x4 bff = *(const f32x4*)(bias + 1024 + u0);
  f32x4 bc = *(const f32x4*)(bias + 2048 + u0);
  f32x4 bo = *(const f32x4*)(bias + 3072 + u0);
  f32x4 ct = *(const f32x4*)(c_tm1 + (size_t)row * 1024 + u0);
  f32x4 hc = *(const f32x4*)(hcro + (size_t)row * 1024 + u0);
  f32x4 h, c;
#pragma unroll
  for (int k = 0; k < 4; ++k) {
    float I = sigm(zi[k] + bi[k]);
    float F = sigm(zf[k] + bff[k]);
    float O = sigm(zo[k] + bo[k]);
    float cc = F * ct[k] + I * tanhf(zc[k] + bc[k]);
    c[k] = cc;
    h[k] = O * tanhf(cc) + hc[k];
  }
  *(f32x4*)(out_h + (size_t)row * 1024 + u0) = h;
  *(f32x4*)(out_c + (size_t)row * 1024 + u0) = c;
}

// ---------- launch ----------
extern "C" void kernel_launch(void* const* d_in, const int* in_sizes, int n_in,
                              void* d_out, int out_size, void* d_ws, size_t ws_size,
                              hipStream_t stream) {
  const float* in_inputs = (const float*)d_in[0];
  const float* in_h      = (const float*)d_in[1];
  const float* in_c      = (const float*)d_in[2];
  const float* in_ctm    = (const float*)d_in[3];
  const float* w_e1      = (const float*)d_in[4];
  const float* w_e2      = (const float*)d_in[5];
  const float* w12w      = (const float*)d_in[6];
  const float* w12u      = (const float*)d_in[7];
  const float* w12v      = (const float*)d_in[8];
  const float* w21w      = (const float*)d_in[9];
  const float* w21u      = (const float*)d_in[10];
  const float* w21v      = (const float*)d_in[11];
  const float* w_cro     = (const float*)d_in[12];
  const float* b_cro     = (const float*)d_in[13];
  const float* w_dec     = (const float*)d_in[14];
  const float* b_dec     = (const float*)d_in[15];
  const float* w_k       = (const float*)d_in[16];
  const float* w_rk      = (const float*)d_in[17];
  const float* b_z       = (const float*)d_in[18];

  float* out_h   = (float*)d_out;
  float* out_c   = out_h + (size_t)2048 * 1024;
  float* out_cro = out_h + (size_t)2 * 2048 * 1024;

  char* ws = (char*)d_ws;
  size_t off = 0;
  auto alloc = [&](size_t bytes) {
    char* p = ws + off;
    off += (bytes + 255) & ~(size_t)255;
    return p;
  };
  u16* BF_IN    = (u16*)alloc((size_t)2048 * 4096 * 2);   // bf16 inputs
  u16* BF_CROTM = (u16*)alloc((size_t)2048 * 2048 * 2);   // bf16 crohis_tm
  u16* E_B      = (u16*)alloc((size_t)2048 * 2048 * 2);   // [e1|e2] bf16
  float* T_ALL  = (float*)alloc((size_t)2048 * 4096 * 4); // [t12|t21|v12|v21]; Z aliases
  float* X_F    = (float*)alloc((size_t)2048 * 2048 * 4);
  u16* XH_B     = (u16*)alloc((size_t)2048 * 3072 * 2);   // [x|h] bf16
  u16* CRO_B    = (u16*)alloc((size_t)2048 * 2048 * 2);   // bf16 new crohis
  float* HCRO   = (float*)alloc((size_t)2048 * 1024 * 4);
  u16* WT_E1    = (u16*)alloc((size_t)1024 * 2048 * 2);
  u16* WT_E2    = (u16*)alloc((size_t)1024 * 2048 * 2);
  u16* WT_ATT   = (u16*)alloc((size_t)4096 * 2048 * 2);   // rows: [t12|t21|v12|v21] x K=2048
  u16* WT_CRO   = (u16*)alloc((size_t)1024 * 2048 * 2);
  u16* WT_DEC   = (u16*)alloc((size_t)2048 * 2048 * 2);
  u16* WT_KRK   = (u16*)alloc((size_t)4096 * 3072 * 2);   // [kernel ; rk] along k
  float* Z = T_ALL;  // 2048x4096 f32, T_ALL dead after softmax

  // zero the padded attention weight buffer (ws is re-poisoned each call)
  hipMemsetAsync(WT_ATT, 0, (size_t)4096 * 2048 * 2, stream);

  // conversions
  cvt_bf16_kernel<<<4096, 256, 0, stream>>>(in_inputs, BF_IN, 1048576);
  cvt_bf16_kernel<<<2048, 256, 0, stream>>>(in_ctm, BF_CROTM, 524288);
  cvt_h_kernel<<<1024, 256, 0, stream>>>(in_h, XH_B);
  // weight transposes (src KxN -> dst NxK slices)
  transpose_cvt<<<dim3(32, 64), 256, 0, stream>>>(w_e1, 2048, 1024, WT_E1, 2048, 0);
  transpose_cvt<<<dim3(32, 64), 256, 0, stream>>>(w_e2, 2048, 1024, WT_E2, 2048, 0);
  // WT_ATT rows 0..1023   (t12): [w12_w ; w12_u]
  transpose_cvt<<<dim3(32, 32), 256, 0, stream>>>(w12w, 1024, 1024, WT_ATT, 2048, 0);
  transpose_cvt<<<dim3(32, 32), 256, 0, stream>>>(w12u, 1024, 1024, WT_ATT, 2048, 1024);
  // WT_ATT rows 1024..2047 (t21): [w21_u ; w21_w]
  transpose_cvt<<<dim3(32, 32), 256, 0, stream>>>(w21u, 1024, 1024, WT_ATT, 2048,
                                                  (long long)1024 * 2048);
  transpose_cvt<<<dim3(32, 32), 256, 0, stream>>>(w21w, 1024, 1024, WT_ATT, 2048,
                                                  (long long)1024 * 2048 + 1024);
  // WT_ATT rows 2048..3071 (v12): [0 ; w12_v]
  transpose_cvt<<<dim3(32, 32), 256, 0, stream>>>(w12v, 1024, 1024, WT_ATT, 2048,
                                                  (long long)2048 * 2048 + 1024);
  // WT_ATT rows 3072..4095 (v21): [w21_v ; 0]
  transpose_cvt<<<dim3(32, 32), 256, 0, stream>>>(w21v, 1024, 1024, WT_ATT, 2048,
                                                  (long long)3072 * 2048);
  transpose_cvt<<<dim3(32, 64), 256, 0, stream>>>(w_cro, 2048, 1024, WT_CRO, 2048, 0);
  transpose_cvt<<<dim3(64, 64), 256, 0, stream>>>(w_dec, 2048, 2048, WT_DEC, 2048, 0);
  transpose_cvt<<<dim3(128, 64), 256, 0, stream>>>(w_k, 2048, 4096, WT_KRK, 3072, 0);
  transpose_cvt<<<dim3(128, 32), 256, 0, stream>>>(w_rk, 1024, 4096, WT_KRK, 3072, 2048);

  // e1/e2 embeddings -> bf16 [e1|e2]
  gemm_bt<EPI_BF16><<<dim3(8, 16), 256, 0, stream>>>(BF_IN, 4096, WT_E1, 2048, 1024, 2048,
                                                     nullptr, 0, E_B, 2048, nullptr, nullptr, nullptr);
  gemm_bt<EPI_BF16><<<dim3(8, 16), 256, 0, stream>>>(BF_IN + 2048, 4096, WT_E2, 2048, 1024, 2048,
                                                     nullptr, 0, E_B + 1024, 2048, nullptr, nullptr, nullptr);
  // fused attention-prep: T_ALL = [t12 | t21 | v12 | v21] in one N=4096 GEMM
  gemm_bt<EPI_F32><<<dim3(32, 16), 256, 0, stream>>>(E_B, 2048, WT_ATT, 2048, 4096, 2048,
                                                     T_ALL, 4096, nullptr, 0, nullptr, nullptr, nullptr);
  // softmax + x (writes X_F f32 and XH_B bf16 x-columns)
  softmax_x_kernel<<<4096, 256, 0, stream>>>(T_ALL, E_B, X_F, XH_B);
  // decomp GEMM, fused sigmoid + crohis blend -> out_cro + CRO_B(bf16)
  gemm_bt<EPI_DEC><<<dim3(16, 16), 256, 0, stream>>>(BF_CROTM, 2048, WT_DEC, 2048, 2048, 2048,
                                                     out_cro, 2048, CRO_B, 2048, b_dec, in_ctm, X_F);
  // h_cro = tanh(crohis @ crohis_w + b)
  gemm_bt<EPI_TANH><<<dim3(8, 16), 256, 0, stream>>>(CRO_B, 2048, WT_CRO, 2048, 1024, 2048,
                                                     HCRO, 1024, nullptr, 0, b_cro, nullptr, nullptr);
  // z = [x|h] @ [kernel;rk]  (K=3072)
  gemm_bt<EPI_F32><<<dim3(32, 16), 256, 0, stream>>>(XH_B, 3072, WT_KRK, 2048, 4096, 3072,
                                                     Z, 4096, nullptr, 0, nullptr, nullptr, nullptr);
  // gates -> h, c
  gates_kernel<<<2048, 256, 0, stream>>>(Z, b_z, in_c, HCRO, out_h, out_c);
}

// Round 4
// 519.566 us; speedup vs baseline: 1.2515x; 1.2515x over previous
//
#include <hip/hip_runtime.h>
#include <stdint.h>

typedef unsigned short u16;
typedef __bf16 bf16x8 __attribute__((ext_vector_type(8)));
typedef float f32x4 __attribute__((ext_vector_type(4)));
typedef u16 u16x8 __attribute__((ext_vector_type(8)));

// ---------- helpers ----------
__device__ __forceinline__ u16 bf16_bits(float f) {
  uint32_t x = __float_as_uint(f);
  uint32_t r = (x + 0x7FFFu + ((x >> 16) & 1u)) >> 16;
  return (u16)r;
}
__device__ __forceinline__ float bits_f32(u16 u) {
  return __uint_as_float(((uint32_t)u) << 16);
}
__device__ __forceinline__ float sigm(float x) { return 1.f / (1.f + expf(-x)); }

__device__ __forceinline__ void gload_lds16(const void* g, void* l) {
  // async global->LDS, 16B/lane; LDS dest = wave-uniform base + lane*16
  __builtin_amdgcn_global_load_lds(
      (const __attribute__((address_space(1))) void*)g,
      (__attribute__((address_space(3))) void*)l,
      16, 0, 0);
}

// ---------- fused conversions (inputs, crohis_tm, h_tm1) ----------
// i < 1048576           : inputs (2048x4096) -> BF_IN
// i < 1048576+524288    : crohis_tm (2048x2048) -> BF_CROTM
// else (262144)         : h_tm1 (2048x1024) -> XH_B cols 2048..3071 (ld 3072)
__global__ __launch_bounds__(256) void cvt_all_kernel(
    const float* __restrict__ inp, const float* __restrict__ ctm,
    const float* __restrict__ h, u16* __restrict__ bf_in,
    u16* __restrict__ bf_ctm, u16* __restrict__ xh) {
  int i = blockIdx.x * 256 + threadIdx.x;
  const float* src;
  u16* dst;
  if (i < 1048576) {
    src = inp + (size_t)i * 8;
    dst = bf_in + (size_t)i * 8;
  } else if (i < 1048576 + 524288) {
    int j = i - 1048576;
    src = ctm + (size_t)j * 8;
    dst = bf_ctm + (size_t)j * 8;
  } else {
    int j = i - 1572864;  // 0..262143
    int row = j >> 7;
    int c0 = (j & 127) << 3;
    src = h + (size_t)row * 1024 + c0;
    dst = xh + (size_t)row * 3072 + 2048 + c0;
  }
  const f32x4* s = (const f32x4*)src;
  f32x4 a = s[0], b = s[1];
  u16x8 o;
#pragma unroll
  for (int k = 0; k < 4; ++k) { o[k] = bf16_bits(a[k]); o[4 + k] = bf16_bits(b[k]); }
  *(u16x8*)dst = o;
}

// ---------- grouped transpose+convert ----------
// per group: src (K x N f32, row-major) -> dst[off + n*ld + k] = bf16(src[k][n])
struct TransGroups {
  const float* src[12];
  u16* dst[12];
  int N[12];
  int ld[12];
  long long off[12];
  int start[13];
};

__global__ __launch_bounds__(256) void transpose_all_kernel(TransGroups tg) {
  __shared__ float t[32][33];
  int bid = blockIdx.x;
  int g = 0;
#pragma unroll
  for (int i = 1; i < 12; ++i)
    if (bid >= tg.start[i]) g = i;
  int local = bid - tg.start[g];
  const float* src = tg.src[g];
  u16* dst = tg.dst[g];
  int N = tg.N[g];
  int ld = tg.ld[g];
  long long off = tg.off[g];
  int ntx = N >> 5;
  int n0 = (local % ntx) << 5;
  int k0 = (local / ntx) << 5;
  int tx = threadIdx.x & 31, ty = threadIdx.x >> 5;  // 32 x 8
#pragma unroll
  for (int r = ty; r < 32; r += 8) t[r][tx] = src[(size_t)(k0 + r) * N + n0 + tx];
  __syncthreads();
#pragma unroll
  for (int r = ty; r < 32; r += 8)
    dst[off + (size_t)(n0 + r) * ld + k0 + tx] = bf16_bits(t[tx][r]);
}

// ---------- grouped GEMM: C(MxN) = A(MxK,bf16) * Bt(NxK,bf16)^T ----------
enum { EPI_F32 = 0, EPI_BF16 = 1, EPI_DHALF = 2, EPI_TANH = 3 };

struct GemmGroups {
  const u16* A[4];
  const u16* Bt[4];
  float* C[4];
  u16* Cb[4];
  const float* bias[4];
  const float* aux[4];
  int lda[4];
  int K[4];
  int nbx[4];
  int ldc[4];
  int ldcb[4];
  int epi[4];
  int start[4];  // unused slots = INT_MAX
};

__global__ __launch_bounds__(256) void gemm_grouped(GemmGroups gg) {
  __shared__ u16 As[128 * 32];
  __shared__ u16 Bs[128 * 32];
  const int bid = blockIdx.x;
  int g = 0;
#pragma unroll
  for (int i = 1; i < 4; ++i)
    if (bid >= gg.start[i]) g = i;
  const int local = bid - gg.start[g];
  const u16* __restrict__ A = gg.A[g];
  const u16* __restrict__ Bt = gg.Bt[g];
  const int lda = gg.lda[g];
  const int K = gg.K[g];
  const int nbx = gg.nbx[g];

  const int tid = threadIdx.x;
  const int lane = tid & 63;
  const int wid = tid >> 6;
  const int wr = wid >> 1, wc = wid & 1;
  const int brow = (local / nbx) * 128;
  const int bcol = (local % nbx) * 128;

  f32x4 acc[4][4] = {};

  const int s0 = wid, s1 = wid + 4;       // 1KB segments this wave stages
  const int oA0 = s0 * 1024 + lane * 16;  // linear byte offset in 8KB tile
  const int oA1 = s1 * 1024 + lane * 16;

  const int nk = K >> 5;
  for (int kt = 0; kt < nk; ++kt) {
    __syncthreads();
    {
      const char* gp;
      int o = oA0;
      gp = (const char*)A + (((size_t)(brow + (o >> 6)) * lda) << 1) + (kt << 6) + (o & 63);
      gload_lds16(gp, (char*)As + s0 * 1024);
      o = oA1;
      gp = (const char*)A + (((size_t)(brow + (o >> 6)) * lda) << 1) + (kt << 6) + (o & 63);
      gload_lds16(gp, (char*)As + s1 * 1024);
      o = oA0;
      gp = (const char*)Bt + (((size_t)(bcol + (o >> 6)) * K) << 1) + (kt << 6) + (o & 63);
      gload_lds16(gp, (char*)Bs + s0 * 1024);
      o = oA1;
      gp = (const char*)Bt + (((size_t)(bcol + (o >> 6)) * K) << 1) + (kt << 6) + (o & 63);
      gload_lds16(gp, (char*)Bs + s1 * 1024);
    }
    __syncthreads();

    bf16x8 af[4], bf[4];
#pragma unroll
    for (int m = 0; m < 4; ++m) {
      int r = wr * 64 + m * 16 + (lane & 15);
      af[m] = *(const bf16x8*)((const char*)As + r * 64 + ((lane >> 4) << 4));
    }
#pragma unroll
    for (int n = 0; n < 4; ++n) {
      int cidx = wc * 64 + n * 16 + (lane & 15);
      bf[n] = *(const bf16x8*)((const char*)Bs + cidx * 64 + ((lane >> 4) << 4));
    }
#pragma unroll
    for (int m = 0; m < 4; ++m)
#pragma unroll
      for (int n = 0; n < 4; ++n)
        acc[m][n] = __builtin_amdgcn_mfma_f32_16x16x32_bf16(af[m], bf[n], acc[m][n], 0, 0, 0);
  }

  float* __restrict__ C = gg.C[g];
  u16* __restrict__ Cb = gg.Cb[g];
  const float* __restrict__ bias = gg.bias[g];
  const float* __restrict__ aux = gg.aux[g];
  const int ldc = gg.ldc[g];
  const int ldcb = gg.ldcb[g];
  const int epi = gg.epi[g];

  const int r0 = brow + wr * 64 + ((lane >> 4) << 2);
  const int c0 = bcol + wc * 64 + (lane & 15);
#pragma unroll
  for (int m = 0; m < 4; ++m) {
#pragma unroll
    for (int n = 0; n < 4; ++n) {
#pragma unroll
      for (int j = 0; j < 4; ++j) {
        int gr = r0 + m * 16 + j;
        int gc = c0 + n * 16;
        float v = acc[m][n][j];
        if (epi == EPI_F32) {
          C[(size_t)gr * ldc + gc] = v;
        } else if (epi == EPI_BF16) {
          Cb[(size_t)gr * ldcb + gc] = bf16_bits(v);
        } else if (epi == EPI_DHALF) {
          size_t ci = (size_t)gr * ldc + gc;
          C[ci] = 0.5f * aux[ci] * sigm(v + bias[gc]);
        } else {  // EPI_TANH
          C[(size_t)gr * ldc + gc] = tanhf(v + bias[gc]);
        }
      }
    }
  }
}

// ---------- softmax + x + crohis blend ----------
// T_ALL row layout (ld 4096): [t12 | t21 | v12 | v21], each 1024 wide.
// block = (row, half): s = tanh(t)*v; ca = softmax(s); x = e*ca;
// cro = DCRO + 0.5*x  (DCRO = 0.5*ctm*sigmoid(decomp) from G1)
__global__ __launch_bounds__(256) void softmax_cro_kernel(
    const float* __restrict__ T_ALL, const u16* __restrict__ E_B,
    const float* __restrict__ DCRO, u16* __restrict__ XH_B,
    float* __restrict__ out_cro, u16* __restrict__ CRO_B) {
  __shared__ float smx[4], sms[4];
  int row = blockIdx.x >> 1;
  int half = blockIdx.x & 1;
  const float* T = T_ALL + (size_t)row * 4096 + half * 1024;         // t12 / t21
  const float* V = T_ALL + (size_t)row * 4096 + 2048 + half * 1024;  // v12 / v21
  int tid = threadIdx.x;
  float s[4];
  float lmax = -1e30f;
#pragma unroll
  for (int i = 0; i < 4; ++i) {
    int c = tid + (i << 8);
    s[i] = tanhf(T[c]) * V[c];
    lmax = fmaxf(lmax, s[i]);
  }
#pragma unroll
  for (int o = 32; o; o >>= 1) lmax = fmaxf(lmax, __shfl_xor(lmax, o, 64));
  if ((tid & 63) == 0) smx[tid >> 6] = lmax;
  __syncthreads();
  float bmax = fmaxf(fmaxf(smx[0], smx[1]), fmaxf(smx[2], smx[3]));
  float lsum = 0.f;
#pragma unroll
  for (int i = 0; i < 4; ++i) { s[i] = expf(s[i] - bmax); lsum += s[i]; }
#pragma unroll
  for (int o = 32; o; o >>= 1) lsum += __shfl_xor(lsum, o, 64);
  if ((tid & 63) == 0) sms[tid >> 6] = lsum;
  __syncthreads();
  float inv = 1.f / (sms[0] + sms[1] + sms[2] + sms[3]);
#pragma unroll
  for (int i = 0; i < 4; ++i) {
    int c = tid + (i << 8);
    int col = half * 1024 + c;
    size_t mi = (size_t)row * 2048 + col;
    float x = bits_f32(E_B[mi]) * s[i] * inv;
    XH_B[(size_t)row * 3072 + col] = bf16_bits(x);
    float cro = DCRO[mi] + 0.5f * x;
    out_cro[mi] = cro;
    CRO_B[mi] = bf16_bits(cro);
  }
}

// ---------- LSTM gates ----------
__global__ __launch_bounds__(256) void gates_kernel(
    const float* __restrict__ Z, const float* __restrict__ bias,
    const float* __restrict__ c_tm1, const float* __restrict__ hcro,
    float* __restrict__ out_h, float* __restrict__ out_c) {
  int i = blockIdx.x * 256 + threadIdx.x;  // 0..524287, 4 units each
  int row = i >> 8;
  int u0 = (i & 255) << 2;
  const float* zr = Z + (size_t)row * 4096;
  f32x4 zi = *(const f32x4*)(zr + u0);
  f32x4 zf = *(const f32x4*)(zr + 1024 + u0);
  f32x4 zc = *(const f32x4*)(zr + 2048 + u0);
  f32x4 zo = *(const f32x4*)(zr + 3072 + u0);
  f32x4 bi = *(const f32x4*)(bias + u0);
  f32x4 bff = *(const f32x4*)(bias + 1024 + u0);
  f32x4 bc = *(const f32x4*)(bias + 2048 + u0);
  f32x4 bo = *(const f32x4*)(bias + 3072 + u0);
  f32x4 ct = *(const f32x4*)(c_tm1 + (size_t)row * 1024 + u0);
  f32x4 hc = *(const f32x4*)(hcro + (size_t)row * 1024 + u0);
  f32x4 h, c;
#pragma unroll
  for (int k = 0; k < 4; ++k) {
    float I = sigm(zi[k] + bi[k]);
    float F = sigm(zf[k] + bff[k]);
    float O = sigm(zo[k] + bo[k]);
    float cc = F * ct[k] + I * tanhf(zc[k] + bc[k]);
    c[k] = cc;
    h[k] = O * tanhf(cc) + hc[k];
  }
  *(f32x4*)(out_h + (size_t)row * 1024 + u0) = h;
  *(f32x4*)(out_c + (size_t)row * 1024 + u0) = c;
}

// ---------- launch ----------
extern "C" void kernel_launch(void* const* d_in, const int* in_sizes, int n_in,
                              void* d_out, int out_size, void* d_ws, size_t ws_size,
                              hipStream_t stream) {
  const float* in_inputs = (const float*)d_in[0];
  const float* in_h      = (const float*)d_in[1];
  const float* in_c      = (const float*)d_in[2];
  const float* in_ctm    = (const float*)d_in[3];
  const float* w_e1      = (const float*)d_in[4];
  const float* w_e2      = (const float*)d_in[5];
  const float* w12w      = (const float*)d_in[6];
  const float* w12u      = (const float*)d_in[7];
  const float* w12v      = (const float*)d_in[8];
  const float* w21w      = (const float*)d_in[9];
  const float* w21u      = (const float*)d_in[10];
  const float* w21v      = (const float*)d_in[11];
  const float* w_cro     = (const float*)d_in[12];
  const float* b_cro     = (const float*)d_in[13];
  const float* w_dec     = (const float*)d_in[14];
  const float* b_dec     = (const float*)d_in[15];
  const float* w_k       = (const float*)d_in[16];
  const float* w_rk      = (const float*)d_in[17];
  const float* b_z       = (const float*)d_in[18];

  float* out_h   = (float*)d_out;
  float* out_c   = out_h + (size_t)2048 * 1024;
  float* out_cro = out_h + (size_t)2 * 2048 * 1024;

  char* ws = (char*)d_ws;
  size_t off = 0;
  auto alloc = [&](size_t bytes) {
    char* p = ws + off;
    off += (bytes + 255) & ~(size_t)255;
    return p;
  };
  u16* BF_IN    = (u16*)alloc((size_t)2048 * 4096 * 2);   // bf16 inputs
  u16* BF_CROTM = (u16*)alloc((size_t)2048 * 2048 * 2);   // bf16 crohis_tm
  u16* E_B      = (u16*)alloc((size_t)2048 * 2048 * 2);   // [e1|e2] bf16
  float* T_ALL  = (float*)alloc((size_t)2048 * 4096 * 4); // [t12|t21|v12|v21]; Z aliases
  float* DCRO   = (float*)alloc((size_t)2048 * 2048 * 4); // 0.5*ctm*sigmoid(decomp)
  u16* XH_B     = (u16*)alloc((size_t)2048 * 3072 * 2);   // [x|h] bf16
  u16* CRO_B    = (u16*)alloc((size_t)2048 * 2048 * 2);   // bf16 new crohis
  float* HCRO   = (float*)alloc((size_t)2048 * 1024 * 4);
  u16* WT_E1    = (u16*)alloc((size_t)1024 * 2048 * 2);
  u16* WT_E2    = (u16*)alloc((size_t)1024 * 2048 * 2);
  u16* WT_T     = (u16*)alloc((size_t)2048 * 2048 * 2);   // rows [t12|t21] x K=2048
  u16* WT_V12   = (u16*)alloc((size_t)1024 * 1024 * 2);
  u16* WT_V21   = (u16*)alloc((size_t)1024 * 1024 * 2);
  u16* WT_CRO   = (u16*)alloc((size_t)1024 * 2048 * 2);
  u16* WT_DEC   = (u16*)alloc((size_t)2048 * 2048 * 2);
  u16* WT_KRK   = (u16*)alloc((size_t)4096 * 3072 * 2);   // [kernel ; rk] along k
  float* Z = T_ALL;  // 2048x4096 f32, T_ALL dead after softmax

  const int INF = 0x7fffffff;

  // 1) fused conversions: 1835008 threads
  cvt_all_kernel<<<7168, 256, 0, stream>>>(in_inputs, in_ctm, in_h, BF_IN, BF_CROTM, XH_B);

  // 2) grouped weight transposes (12 groups, 28672 tile-blocks)
  {
    TransGroups tg;
    int s = 0, gi = 0;
    auto add = [&](const float* src, int K, int N, u16* dst, int ld, long long dOff) {
      tg.src[gi] = src; tg.dst[gi] = dst; tg.N[gi] = N; tg.ld[gi] = ld; tg.off[gi] = dOff;
      tg.start[gi] = s; s += (K >> 5) * (N >> 5); ++gi;
    };
    add(w_e1, 2048, 1024, WT_E1, 2048, 0);
    add(w_e2, 2048, 1024, WT_E2, 2048, 0);
    add(w12w, 1024, 1024, WT_T, 2048, 0);
    add(w12u, 1024, 1024, WT_T, 2048, 1024);
    add(w21u, 1024, 1024, WT_T, 2048, (long long)1024 * 2048);
    add(w21w, 1024, 1024, WT_T, 2048, (long long)1024 * 2048 + 1024);
    add(w12v, 1024, 1024, WT_V12, 1024, 0);
    add(w21v, 1024, 1024, WT_V21, 1024, 0);
    add(w_cro, 2048, 1024, WT_CRO, 2048, 0);
    add(w_dec, 2048, 2048, WT_DEC, 2048, 0);
    add(w_k, 2048, 4096, WT_KRK, 3072, 0);
    add(w_rk, 1024, 4096, WT_KRK, 3072, 2048);
    tg.start[12] = s;
    transpose_all_kernel<<<s, 256, 0, stream>>>(tg);
  }

  auto mkgrp = [&]() {
    GemmGroups gg;
    for (int i = 0; i < 4; ++i) {
      gg.A[i] = nullptr; gg.Bt[i] = nullptr; gg.C[i] = nullptr; gg.Cb[i] = nullptr;
      gg.bias[i] = nullptr; gg.aux[i] = nullptr;
      gg.lda[i] = 0; gg.K[i] = 32; gg.nbx[i] = 1; gg.ldc[i] = 0; gg.ldcb[i] = 0;
      gg.epi[i] = EPI_F32; gg.start[i] = INF;
    }
    return gg;
  };

  // 3) G1: decomp(256) | e1(128) | e2(128)  -> 512 blocks
  {
    GemmGroups gg = mkgrp();
    // g0: DCRO = 0.5*ctm*sigmoid(ctm@w_dec + b_dec)
    gg.A[0] = BF_CROTM; gg.Bt[0] = WT_DEC; gg.lda[0] = 2048; gg.K[0] = 2048;
    gg.nbx[0] = 16; gg.C[0] = DCRO; gg.ldc[0] = 2048; gg.epi[0] = EPI_DHALF;
    gg.bias[0] = b_dec; gg.aux[0] = in_ctm; gg.start[0] = 0;
    // g1: e1 -> E_B cols 0..1023 (bf16)
    gg.A[1] = BF_IN; gg.Bt[1] = WT_E1; gg.lda[1] = 4096; gg.K[1] = 2048;
    gg.nbx[1] = 8; gg.Cb[1] = E_B; gg.ldcb[1] = 2048; gg.epi[1] = EPI_BF16;
    gg.start[1] = 256;
    // g2: e2 -> E_B cols 1024..2047
    gg.A[2] = BF_IN + 2048; gg.Bt[2] = WT_E2; gg.lda[2] = 4096; gg.K[2] = 2048;
    gg.nbx[2] = 8; gg.Cb[2] = E_B + 1024; gg.ldcb[2] = 2048; gg.epi[2] = EPI_BF16;
    gg.start[2] = 384;
    gemm_grouped<<<512, 256, 0, stream>>>(gg);
  }

  // 4) G2: t12t21(256, K=2048) | v12(128, K=1024) | v21(128, K=1024) -> 512 blocks
  {
    GemmGroups gg = mkgrp();
    gg.A[0] = E_B; gg.Bt[0] = WT_T; gg.lda[0] = 2048; gg.K[0] = 2048;
    gg.nbx[0] = 16; gg.C[0] = T_ALL; gg.ldc[0] = 4096; gg.epi[0] = EPI_F32;
    gg.start[0] = 0;
    gg.A[1] = E_B + 1024; gg.Bt[1] = WT_V12; gg.lda[1] = 2048; gg.K[1] = 1024;
    gg.nbx[1] = 8; gg.C[1] = T_ALL + 2048; gg.ldc[1] = 4096; gg.epi[1] = EPI_F32;
    gg.start[1] = 256;
    gg.A[2] = E_B; gg.Bt[2] = WT_V21; gg.lda[2] = 2048; gg.K[2] = 1024;
    gg.nbx[2] = 8; gg.C[2] = T_ALL + 3072; gg.ldc[2] = 4096; gg.epi[2] = EPI_F32;
    gg.start[2] = 384;
    gemm_grouped<<<512, 256, 0, stream>>>(gg);
  }

  // 5) softmax + x + crohis blend
  softmax_cro_kernel<<<4096, 256, 0, stream>>>(T_ALL, E_B, DCRO, XH_B, out_cro, CRO_B);

  // 6) G3: z(512, K=3072) | h_cro(128, K=2048) -> 640 blocks
  {
    GemmGroups gg = mkgrp();
    gg.A[0] = XH_B; gg.Bt[0] = WT_KRK; gg.lda[0] = 3072; gg.K[0] = 3072;
    gg.nbx[0] = 32; gg.C[0] = Z; gg.ldc[0] = 4096; gg.epi[0] = EPI_F32;
    gg.start[0] = 0;
    gg.A[1] = CRO_B; gg.Bt[1] = WT_CRO; gg.lda[1] = 2048; gg.K[1] = 2048;
    gg.nbx[1] = 8; gg.C[1] = HCRO; gg.ldc[1] = 1024; gg.epi[1] = EPI_TANH;
    gg.bias[1] = b_cro; gg.start[1] = 512;
    gemm_grouped<<<640, 256, 0, stream>>>(gg);
  }

  // 7) gates -> h, c
  gates_kernel<<<2048, 256, 0, stream>>>(Z, b_z, in_c, HCRO, out_h, out_c);
}

// Round 5
// 497.845 us; speedup vs baseline: 1.3061x; 1.0436x over previous
//
#include <hip/hip_runtime.h>
#include <stdint.h>

typedef unsigned short u16;
typedef __bf16 bf16x8 __attribute__((ext_vector_type(8)));
typedef float f32x4 __attribute__((ext_vector_type(4)));
typedef u16 u16x8 __attribute__((ext_vector_type(8)));

// ---------- helpers ----------
__device__ __forceinline__ u16 bf16_bits(float f) {
  uint32_t x = __float_as_uint(f);
  uint32_t r = (x + 0x7FFFu + ((x >> 16) & 1u)) >> 16;
  return (u16)r;
}
__device__ __forceinline__ float bits_f32(u16 u) {
  return __uint_as_float(((uint32_t)u) << 16);
}
__device__ __forceinline__ float sigm(float x) { return 1.f / (1.f + expf(-x)); }

__device__ __forceinline__ void gload_lds16(const void* g, void* l) {
  // async global->LDS, 16B/lane; LDS dest = wave-uniform base + lane*16
  __builtin_amdgcn_global_load_lds(
      (const __attribute__((address_space(1))) void*)g,
      (__attribute__((address_space(3))) void*)l,
      16, 0, 0);
}

// ---------- fused conversions (inputs, crohis_tm, h_tm1) ----------
__global__ __launch_bounds__(256) void cvt_all_kernel(
    const float* __restrict__ inp, const float* __restrict__ ctm,
    const float* __restrict__ h, u16* __restrict__ bf_in,
    u16* __restrict__ bf_ctm, u16* __restrict__ xh) {
  int i = blockIdx.x * 256 + threadIdx.x;
  const float* src;
  u16* dst;
  if (i < 1048576) {
    src = inp + (size_t)i * 8;
    dst = bf_in + (size_t)i * 8;
  } else if (i < 1048576 + 524288) {
    int j = i - 1048576;
    src = ctm + (size_t)j * 8;
    dst = bf_ctm + (size_t)j * 8;
  } else {
    int j = i - 1572864;  // 0..262143
    int row = j >> 7;
    int c0 = (j & 127) << 3;
    src = h + (size_t)row * 1024 + c0;
    dst = xh + (size_t)row * 3072 + 2048 + c0;
  }
  const f32x4* s = (const f32x4*)src;
  f32x4 a = s[0], b = s[1];
  u16x8 o;
#pragma unroll
  for (int k = 0; k < 4; ++k) { o[k] = bf16_bits(a[k]); o[4 + k] = bf16_bits(b[k]); }
  *(u16x8*)dst = o;
}

// ---------- grouped transpose+convert ----------
// per group: src (K x N f32, row-major) -> dst[off + n*ld + k] = bf16(src[k][n])
// tiles: 64(k) x 32(n); stores 2 bf16 packed as u32 -> 128B contiguous segments
struct TransGroups {
  const float* src[12];
  u16* dst[12];
  int N[12];
  int ld[12];
  long long off[12];
  int start[13];
};

__global__ __launch_bounds__(256) void transpose_all_kernel(TransGroups tg) {
  __shared__ float t[64][33];
  int bid = blockIdx.x;
  int g = 0;
#pragma unroll
  for (int i = 1; i < 12; ++i)
    if (bid >= tg.start[i]) g = i;
  int local = bid - tg.start[g];
  const float* src = tg.src[g];
  u16* dst = tg.dst[g];
  int N = tg.N[g];
  int ld = tg.ld[g];
  long long off = tg.off[g];
  int ntn = N >> 5;
  int n0 = (local % ntn) << 5;
  int k0 = (local / ntn) << 6;
  int tx = threadIdx.x & 31, ty = threadIdx.x >> 5;  // 32 x 8
#pragma unroll
  for (int r = ty; r < 64; r += 8) t[r][tx] = src[(size_t)(k0 + r) * N + n0 + tx];
  __syncthreads();
#pragma unroll
  for (int j = ty; j < 32; j += 8) {
    uint32_t lo = bf16_bits(t[2 * tx][j]);
    uint32_t hi = bf16_bits(t[2 * tx + 1][j]);
    *(uint32_t*)(&dst[off + (size_t)(n0 + j) * ld + k0 + 2 * tx]) = lo | (hi << 16);
  }
}

// ---------- grouped GEMM: C(MxN) = A(MxK,bf16) * Bt(NxK,bf16)^T ----------
// Double-buffered LDS: STAGE(next tile) issued BEFORE compute(cur), one
// barrier per K-step -> load flight overlaps ds_read+MFMA (T3-minimum).
enum { EPI_F32 = 0, EPI_BF16 = 1, EPI_DHALF = 2, EPI_TANH = 3 };

struct GemmGroups {
  const u16* A[4];
  const u16* Bt[4];
  float* C[4];
  u16* Cb[4];
  const float* bias[4];
  const float* aux[4];
  int lda[4];
  int K[4];
  int nbx[4];
  int ldc[4];
  int ldcb[4];
  int epi[4];
  int start[4];  // unused slots = INT_MAX
};

__global__ __launch_bounds__(256) void gemm_grouped(GemmGroups gg) {
  __shared__ u16 As[2][4096];  // 2 x 8KB
  __shared__ u16 Bs[2][4096];
  const int bid = blockIdx.x;
  int g = 0;
#pragma unroll
  for (int i = 1; i < 4; ++i)
    if (bid >= gg.start[i]) g = i;
  const int local = bid - gg.start[g];
  const u16* __restrict__ A = gg.A[g];
  const u16* __restrict__ Bt = gg.Bt[g];
  const int lda = gg.lda[g];
  const int K = gg.K[g];
  const int nbx = gg.nbx[g];

  const int tid = threadIdx.x;
  const int lane = tid & 63;
  const int wid = tid >> 6;
  const int wr = wid >> 1, wc = wid & 1;
  const int brow = (local / nbx) * 128;
  const int bcol = (local % nbx) * 128;

  f32x4 acc[4][4] = {};

  const int s0 = wid, s1 = wid + 4;       // 1KB segments this wave stages
  const int oA0 = s0 * 1024 + lane * 16;  // linear byte offset in 8KB tile
  const int oA1 = s1 * 1024 + lane * 16;

  // per-lane global base pointers (k-offset added per stage)
  const char* gA0 = (const char*)A + (((size_t)(brow + (oA0 >> 6)) * lda) << 1) + (oA0 & 63);
  const char* gA1 = (const char*)A + (((size_t)(brow + (oA1 >> 6)) * lda) << 1) + (oA1 & 63);
  const char* gB0 = (const char*)Bt + (((size_t)(bcol + (oA0 >> 6)) * K) << 1) + (oA0 & 63);
  const char* gB1 = (const char*)Bt + (((size_t)(bcol + (oA1 >> 6)) * K) << 1) + (oA1 & 63);

#define STAGE(buf, koff)                                              \
  {                                                                   \
    gload_lds16(gA0 + (koff), (char*)As + (buf) * 8192 + s0 * 1024);  \
    gload_lds16(gA1 + (koff), (char*)As + (buf) * 8192 + s1 * 1024);  \
    gload_lds16(gB0 + (koff), (char*)Bs + (buf) * 8192 + s0 * 1024);  \
    gload_lds16(gB1 + (koff), (char*)Bs + (buf) * 8192 + s1 * 1024);  \
  }

  const int nk = K >> 5;
  STAGE(0, 0);
  __syncthreads();  // drains staging of tile 0
  int cur = 0;
  for (int kt = 0; kt < nk; ++kt) {
    const int koff = (kt + 1 < nk ? kt + 1 : kt) << 6;  // last iter: harmless re-stage
    STAGE(cur ^ 1, koff);  // prefetch next tile; flight overlaps compute below

    const char* Ab = (const char*)As + cur * 8192;
    const char* Bb = (const char*)Bs + cur * 8192;
    bf16x8 af[4], bfr[4];
#pragma unroll
    for (int m = 0; m < 4; ++m) {
      int r = wr * 64 + m * 16 + (lane & 15);
      af[m] = *(const bf16x8*)(Ab + r * 64 + ((lane >> 4) << 4));
    }
#pragma unroll
    for (int n = 0; n < 4; ++n) {
      int cidx = wc * 64 + n * 16 + (lane & 15);
      bfr[n] = *(const bf16x8*)(Bb + cidx * 64 + ((lane >> 4) << 4));
    }
#pragma unroll
    for (int m = 0; m < 4; ++m)
#pragma unroll
      for (int n = 0; n < 4; ++n)
        acc[m][n] = __builtin_amdgcn_mfma_f32_16x16x32_bf16(af[m], bfr[n], acc[m][n], 0, 0, 0);

    __syncthreads();  // all waves done reading cur; next-tile staging drained
    cur ^= 1;
  }
#undef STAGE

  float* __restrict__ C = gg.C[g];
  u16* __restrict__ Cb = gg.Cb[g];
  const float* __restrict__ bias = gg.bias[g];
  const float* __restrict__ aux = gg.aux[g];
  const int ldc = gg.ldc[g];
  const int ldcb = gg.ldcb[g];
  const int epi = gg.epi[g];

  const int r0 = brow + wr * 64 + ((lane >> 4) << 2);
  const int c0 = bcol + wc * 64 + (lane & 15);
#pragma unroll
  for (int m = 0; m < 4; ++m) {
#pragma unroll
    for (int n = 0; n < 4; ++n) {
#pragma unroll
      for (int j = 0; j < 4; ++j) {
        int gr = r0 + m * 16 + j;
        int gc = c0 + n * 16;
        float v = acc[m][n][j];
        if (epi == EPI_F32) {
          C[(size_t)gr * ldc + gc] = v;
        } else if (epi == EPI_BF16) {
          Cb[(size_t)gr * ldcb + gc] = bf16_bits(v);
        } else if (epi == EPI_DHALF) {
          size_t ci = (size_t)gr * ldc + gc;
          C[ci] = 0.5f * aux[ci] * sigm(v + bias[gc]);
        } else {  // EPI_TANH
          C[(size_t)gr * ldc + gc] = tanhf(v + bias[gc]);
        }
      }
    }
  }
}

// ---------- softmax + x + crohis blend ----------
// T_ALL row layout (ld 4096): [t12 | t21 | v12 | v21], each 1024 wide.
__global__ __launch_bounds__(256) void softmax_cro_kernel(
    const float* __restrict__ T_ALL, const u16* __restrict__ E_B,
    const float* __restrict__ DCRO, u16* __restrict__ XH_B,
    float* __restrict__ out_cro, u16* __restrict__ CRO_B) {
  __shared__ float smx[4], sms[4];
  int row = blockIdx.x >> 1;
  int half = blockIdx.x & 1;
  const float* T = T_ALL + (size_t)row * 4096 + half * 1024;         // t12 / t21
  const float* V = T_ALL + (size_t)row * 4096 + 2048 + half * 1024;  // v12 / v21
  int tid = threadIdx.x;
  float s[4];
  float lmax = -1e30f;
#pragma unroll
  for (int i = 0; i < 4; ++i) {
    int c = tid + (i << 8);
    s[i] = tanhf(T[c]) * V[c];
    lmax = fmaxf(lmax, s[i]);
  }
#pragma unroll
  for (int o = 32; o; o >>= 1) lmax = fmaxf(lmax, __shfl_xor(lmax, o, 64));
  if ((tid & 63) == 0) smx[tid >> 6] = lmax;
  __syncthreads();
  float bmax = fmaxf(fmaxf(smx[0], smx[1]), fmaxf(smx[2], smx[3]));
  float lsum = 0.f;
#pragma unroll
  for (int i = 0; i < 4; ++i) { s[i] = expf(s[i] - bmax); lsum += s[i]; }
#pragma unroll
  for (int o = 32; o; o >>= 1) lsum += __shfl_xor(lsum, o, 64);
  if ((tid & 63) == 0) sms[tid >> 6] = lsum;
  __syncthreads();
  float inv = 1.f / (sms[0] + sms[1] + sms[2] + sms[3]);
#pragma unroll
  for (int i = 0; i < 4; ++i) {
    int c = tid + (i << 8);
    int col = half * 1024 + c;
    size_t mi = (size_t)row * 2048 + col;
    float x = bits_f32(E_B[mi]) * s[i] * inv;
    XH_B[(size_t)row * 3072 + col] = bf16_bits(x);
    float cro = DCRO[mi] + 0.5f * x;
    out_cro[mi] = cro;
    CRO_B[mi] = bf16_bits(cro);
  }
}

// ---------- LSTM gates ----------
__global__ __launch_bounds__(256) void gates_kernel(
    const float* __restrict__ Z, const float* __restrict__ bias,
    const float* __restrict__ c_tm1, const float* __restrict__ hcro,
    float* __restrict__ out_h, float* __restrict__ out_c) {
  int i = blockIdx.x * 256 + threadIdx.x;  // 0..524287, 4 units each
  int row = i >> 8;
  int u0 = (i & 255) << 2;
  const float* zr = Z + (size_t)row * 4096;
  f32x4 zi = *(const f32x4*)(zr + u0);
  f32x4 zf = *(const f32x4*)(zr + 1024 + u0);
  f32x4 zc = *(const f32x4*)(zr + 2048 + u0);
  f32x4 zo = *(const f32x4*)(zr + 3072 + u0);
  f32x4 bi = *(const f32x4*)(bias + u0);
  f32x4 bff = *(const f32x4*)(bias + 1024 + u0);
  f32x4 bc = *(const f32x4*)(bias + 2048 + u0);
  f32x4 bo = *(const f32x4*)(bias + 3072 + u0);
  f32x4 ct = *(const f32x4*)(c_tm1 + (size_t)row * 1024 + u0);
  f32x4 hc = *(const f32x4*)(hcro + (size_t)row * 1024 + u0);
  f32x4 h, c;
#pragma unroll
  for (int k = 0; k < 4; ++k) {
    float I = sigm(zi[k] + bi[k]);
    float F = sigm(zf[k] + bff[k]);
    float O = sigm(zo[k] + bo[k]);
    float cc = F * ct[k] + I * tanhf(zc[k] + bc[k]);
    c[k] = cc;
    h[k] = O * tanhf(cc) + hc[k];
  }
  *(f32x4*)(out_h + (size_t)row * 1024 + u0) = h;
  *(f32x4*)(out_c + (size_t)row * 1024 + u0) = c;
}

// ---------- launch ----------
extern "C" void kernel_launch(void* const* d_in, const int* in_sizes, int n_in,
                              void* d_out, int out_size, void* d_ws, size_t ws_size,
                              hipStream_t stream) {
  const float* in_inputs = (const float*)d_in[0];
  const float* in_h      = (const float*)d_in[1];
  const float* in_c      = (const float*)d_in[2];
  const float* in_ctm    = (const float*)d_in[3];
  const float* w_e1      = (const float*)d_in[4];
  const float* w_e2      = (const float*)d_in[5];
  const float* w12w      = (const float*)d_in[6];
  const float* w12u      = (const float*)d_in[7];
  const float* w12v      = (const float*)d_in[8];
  const float* w21w      = (const float*)d_in[9];
  const float* w21u      = (const float*)d_in[10];
  const float* w21v      = (const float*)d_in[11];
  const float* w_cro     = (const float*)d_in[12];
  const float* b_cro     = (const float*)d_in[13];
  const float* w_dec     = (const float*)d_in[14];
  const float* b_dec     = (const float*)d_in[15];
  const float* w_k       = (const float*)d_in[16];
  const float* w_rk      = (const float*)d_in[17];
  const float* b_z       = (const float*)d_in[18];

  float* out_h   = (float*)d_out;
  float* out_c   = out_h + (size_t)2048 * 1024;
  float* out_cro = out_h + (size_t)2 * 2048 * 1024;

  char* ws = (char*)d_ws;
  size_t off = 0;
  auto alloc = [&](size_t bytes) {
    char* p = ws + off;
    off += (bytes + 255) & ~(size_t)255;
    return p;
  };
  u16* BF_IN    = (u16*)alloc((size_t)2048 * 4096 * 2);   // bf16 inputs
  u16* BF_CROTM = (u16*)alloc((size_t)2048 * 2048 * 2);   // bf16 crohis_tm
  u16* E_B      = (u16*)alloc((size_t)2048 * 2048 * 2);   // [e1|e2] bf16
  float* T_ALL  = (float*)alloc((size_t)2048 * 4096 * 4); // [t12|t21|v12|v21]; Z aliases
  float* DCRO   = (float*)alloc((size_t)2048 * 2048 * 4); // 0.5*ctm*sigmoid(decomp)
  u16* XH_B     = (u16*)alloc((size_t)2048 * 3072 * 2);   // [x|h] bf16
  u16* CRO_B    = (u16*)alloc((size_t)2048 * 2048 * 2);   // bf16 new crohis
  float* HCRO   = (float*)alloc((size_t)2048 * 1024 * 4);
  u16* WT_E1    = (u16*)alloc((size_t)1024 * 2048 * 2);
  u16* WT_E2    = (u16*)alloc((size_t)1024 * 2048 * 2);
  u16* WT_T     = (u16*)alloc((size_t)2048 * 2048 * 2);   // rows [t12|t21] x K=2048
  u16* WT_V12   = (u16*)alloc((size_t)1024 * 1024 * 2);
  u16* WT_V21   = (u16*)alloc((size_t)1024 * 1024 * 2);
  u16* WT_CRO   = (u16*)alloc((size_t)1024 * 2048 * 2);
  u16* WT_DEC   = (u16*)alloc((size_t)2048 * 2048 * 2);
  u16* WT_KRK   = (u16*)alloc((size_t)4096 * 3072 * 2);   // [kernel ; rk] along k
  float* Z = T_ALL;  // 2048x4096 f32, T_ALL dead after softmax

  const int INF = 0x7fffffff;

  // 1) fused conversions: 1835008 threads
  cvt_all_kernel<<<7168, 256, 0, stream>>>(in_inputs, in_ctm, in_h, BF_IN, BF_CROTM, XH_B);

  // 2) grouped weight transposes (12 groups, 64x32 tiles)
  {
    TransGroups tg;
    int s = 0, gi = 0;
    auto add = [&](const float* src, int K, int N, u16* dst, int ld, long long dOff) {
      tg.src[gi] = src; tg.dst[gi] = dst; tg.N[gi] = N; tg.ld[gi] = ld; tg.off[gi] = dOff;
      tg.start[gi] = s; s += (K >> 6) * (N >> 5); ++gi;
    };
    add(w_e1, 2048, 1024, WT_E1, 2048, 0);
    add(w_e2, 2048, 1024, WT_E2, 2048, 0);
    add(w12w, 1024, 1024, WT_T, 2048, 0);
    add(w12u, 1024, 1024, WT_T, 2048, 1024);
    add(w21u, 1024, 1024, WT_T, 2048, (long long)1024 * 2048);
    add(w21w, 1024, 1024, WT_T, 2048, (long long)1024 * 2048 + 1024);
    add(w12v, 1024, 1024, WT_V12, 1024, 0);
    add(w21v, 1024, 1024, WT_V21, 1024, 0);
    add(w_cro, 2048, 1024, WT_CRO, 2048, 0);
    add(w_dec, 2048, 2048, WT_DEC, 2048, 0);
    add(w_k, 2048, 4096, WT_KRK, 3072, 0);
    add(w_rk, 1024, 4096, WT_KRK, 3072, 2048);
    tg.start[12] = s;
    transpose_all_kernel<<<s, 256, 0, stream>>>(tg);
  }

  auto mkgrp = [&]() {
    GemmGroups gg;
    for (int i = 0; i < 4; ++i) {
      gg.A[i] = nullptr; gg.Bt[i] = nullptr; gg.C[i] = nullptr; gg.Cb[i] = nullptr;
      gg.bias[i] = nullptr; gg.aux[i] = nullptr;
      gg.lda[i] = 0; gg.K[i] = 32; gg.nbx[i] = 1; gg.ldc[i] = 0; gg.ldcb[i] = 0;
      gg.epi[i] = EPI_F32; gg.start[i] = INF;
    }
    return gg;
  };

  // 3) G1: decomp(256) | e1(128) | e2(128)  -> 512 blocks
  {
    GemmGroups gg = mkgrp();
    // g0: DCRO = 0.5*ctm*sigmoid(ctm@w_dec + b_dec)
    gg.A[0] = BF_CROTM; gg.Bt[0] = WT_DEC; gg.lda[0] = 2048; gg.K[0] = 2048;
    gg.nbx[0] = 16; gg.C[0] = DCRO; gg.ldc[0] = 2048; gg.epi[0] = EPI_DHALF;
    gg.bias[0] = b_dec; gg.aux[0] = in_ctm; gg.start[0] = 0;
    // g1: e1 -> E_B cols 0..1023 (bf16)
    gg.A[1] = BF_IN; gg.Bt[1] = WT_E1; gg.lda[1] = 4096; gg.K[1] = 2048;
    gg.nbx[1] = 8; gg.Cb[1] = E_B; gg.ldcb[1] = 2048; gg.epi[1] = EPI_BF16;
    gg.start[1] = 256;
    // g2: e2 -> E_B cols 1024..2047
    gg.A[2] = BF_IN + 2048; gg.Bt[2] = WT_E2; gg.lda[2] = 4096; gg.K[2] = 2048;
    gg.nbx[2] = 8; gg.Cb[2] = E_B + 1024; gg.ldcb[2] = 2048; gg.epi[2] = EPI_BF16;
    gg.start[2] = 384;
    gemm_grouped<<<512, 256, 0, stream>>>(gg);
  }

  // 4) G2: t12t21(256, K=2048) | v12(128, K=1024) | v21(128, K=1024) -> 512 blocks
  {
    GemmGroups gg = mkgrp();
    gg.A[0] = E_B; gg.Bt[0] = WT_T; gg.lda[0] = 2048; gg.K[0] = 2048;
    gg.nbx[0] = 16; gg.C[0] = T_ALL; gg.ldc[0] = 4096; gg.epi[0] = EPI_F32;
    gg.start[0] = 0;
    gg.A[1] = E_B + 1024; gg.Bt[1] = WT_V12; gg.lda[1] = 2048; gg.K[1] = 1024;
    gg.nbx[1] = 8; gg.C[1] = T_ALL + 2048; gg.ldc[1] = 4096; gg.epi[1] = EPI_F32;
    gg.start[1] = 256;
    gg.A[2] = E_B; gg.Bt[2] = WT_V21; gg.lda[2] = 2048; gg.K[2] = 1024;
    gg.nbx[2] = 8; gg.C[2] = T_ALL + 3072; gg.ldc[2] = 4096; gg.epi[2] = EPI_F32;
    gg.start[2] = 384;
    gemm_grouped<<<512, 256, 0, stream>>>(gg);
  }

  // 5) softmax + x + crohis blend
  softmax_cro_kernel<<<4096, 256, 0, stream>>>(T_ALL, E_B, DCRO, XH_B, out_cro, CRO_B);

  // 6) G3: z(512, K=3072) | h_cro(128, K=2048) -> 640 blocks (LPT order)
  {
    GemmGroups gg = mkgrp();
    gg.A[0] = XH_B; gg.Bt[0] = WT_KRK; gg.lda[0] = 3072; gg.K[0] = 3072;
    gg.nbx[0] = 32; gg.C[0] = Z; gg.ldc[0] = 4096; gg.epi[0] = EPI_F32;
    gg.start[0] = 0;
    gg.A[1] = CRO_B; gg.Bt[1] = WT_CRO; gg.lda[1] = 2048; gg.K[1] = 2048;
    gg.nbx[1] = 8; gg.C[1] = HCRO; gg.ldc[1] = 1024; gg.epi[1] = EPI_TANH;
    gg.bias[1] = b_cro; gg.start[1] = 512;
    gemm_grouped<<<640, 256, 0, stream>>>(gg);
  }

  // 7) gates -> h, c
  gates_kernel<<<2048, 256, 0, stream>>>(Z, b_z, in_c, HCRO, out_h, out_c);
}

// Round 12
// 490.308 us; speedup vs baseline: 1.3262x; 1.0154x over previous
//
#include <hip/hip_runtime.h>
#include <stdint.h>

typedef unsigned short u16;
typedef __bf16 bf16x8 __attribute__((ext_vector_type(8)));
typedef float f32x4 __attribute__((ext_vector_type(4)));
typedef u16 u16x8 __attribute__((ext_vector_type(8)));

// ---------- helpers ----------
__device__ __forceinline__ u16 bf16_bits(float f) {
  uint32_t x = __float_as_uint(f);
  uint32_t r = (x + 0x7FFFu + ((x >> 16) & 1u)) >> 16;
  return (u16)r;
}
__device__ __forceinline__ float bits_f32(u16 u) {
  return __uint_as_float(((uint32_t)u) << 16);
}
__device__ __forceinline__ float sigm(float x) { return 1.f / (1.f + expf(-x)); }

__device__ __forceinline__ void gload_lds16(const void* g, void* l) {
  __builtin_amdgcn_global_load_lds(
      (const __attribute__((address_space(1))) void*)g,
      (__attribute__((address_space(3))) void*)l,
      16, 0, 0);
}

// ---------- fused conversions (inputs, crohis_tm, h_tm1) ----------
__global__ __launch_bounds__(256) void cvt_all_kernel(
    const float* __restrict__ inp, const float* __restrict__ ctm,
    const float* __restrict__ h, u16* __restrict__ bf_in,
    u16* __restrict__ bf_ctm, u16* __restrict__ xh) {
  int i = blockIdx.x * 256 + threadIdx.x;
  const float* src;
  u16* dst;
  if (i < 1048576) {
    src = inp + (size_t)i * 8;
    dst = bf_in + (size_t)i * 8;
  } else if (i < 1048576 + 524288) {
    int j = i - 1048576;
    src = ctm + (size_t)j * 8;
    dst = bf_ctm + (size_t)j * 8;
  } else {
    int j = i - 1572864;  // 0..262143
    int row = j >> 7;
    int c0 = (j & 127) << 3;
    src = h + (size_t)row * 1024 + c0;
    dst = xh + (size_t)row * 3072 + 2048 + c0;
  }
  const f32x4* s = (const f32x4*)src;
  f32x4 a = s[0], b = s[1];
  u16x8 o;
#pragma unroll
  for (int k = 0; k < 4; ++k) { o[k] = bf16_bits(a[k]); o[4 + k] = bf16_bits(b[k]); }
  *(u16x8*)dst = o;
}

// ---------- grouped transpose+convert ----------
struct TransGroups {
  const float* src[12];
  u16* dst[12];
  int N[12];
  int ld[12];
  long long off[12];
  int start[13];
};

__global__ __launch_bounds__(256) void transpose_all_kernel(TransGroups tg) {
  __shared__ float t[64][33];
  int bid = blockIdx.x;
  int g = 0;
#pragma unroll
  for (int i = 1; i < 12; ++i)
    if (bid >= tg.start[i]) g = i;
  int local = bid - tg.start[g];
  const float* src = tg.src[g];
  u16* dst = tg.dst[g];
  int N = tg.N[g];
  int ld = tg.ld[g];
  long long off = tg.off[g];
  int ntn = N >> 5;
  int n0 = (local % ntn) << 5;
  int k0 = (local / ntn) << 6;
  int tx = threadIdx.x & 31, ty = threadIdx.x >> 5;  // 32 x 8
#pragma unroll
  for (int r = ty; r < 64; r += 8) t[r][tx] = src[(size_t)(k0 + r) * N + n0 + tx];
  __syncthreads();
#pragma unroll
  for (int j = ty; j < 32; j += 8) {
    uint32_t lo = bf16_bits(t[2 * tx][j]);
    uint32_t hi = bf16_bits(t[2 * tx + 1][j]);
    *(uint32_t*)(&dst[off + (size_t)(n0 + j) * ld + k0 + 2 * tx]) = lo | (hi << 16);
  }
}

// ---------- grouped GEMM: C(MxN) = A(MxK,bf16) * Bt(NxK,bf16)^T ----------
// Double-buffered LDS, 1 barrier/K-step. Split-K partials (f32) for t/z/hcro;
// combines fused into consumers. Decomp unsplit with fused sigmoid+half-blend.
enum { EPI_F32 = 0, EPI_BF16 = 1, EPI_DHALF = 2 };

struct GemmGroups {
  const u16* A[4];
  const u16* Bt[4];
  float* C[4];
  u16* Cb[4];
  const float* bias[4];
  const float* aux[4];
  int lda[4];
  int ldb[4];
  int K[4];
  int nbx[4];
  int ldc[4];
  int ldcb[4];
  int epi[4];
  int start[4];
};

__global__ __launch_bounds__(256) void gemm_grouped(GemmGroups gg) {
  __shared__ u16 As[2][4096];  // 2 x 8KB
  __shared__ u16 Bs[2][4096];
  const int bid = blockIdx.x;
  int g = 0;
#pragma unroll
  for (int i = 1; i < 4; ++i)
    if (bid >= gg.start[i]) g = i;
  const int local = bid - gg.start[g];
  const u16* __restrict__ A = gg.A[g];
  const u16* __restrict__ Bt = gg.Bt[g];
  const int lda = gg.lda[g];
  const int ldb = gg.ldb[g];
  const int K = gg.K[g];
  const int nbx = gg.nbx[g];

  const int tid = threadIdx.x;
  const int lane = tid & 63;
  const int wid = tid >> 6;
  const int wr = wid >> 1, wc = wid & 1;
  const int brow = (local / nbx) * 128;
  const int bcol = (local % nbx) * 128;

  f32x4 acc[4][4] = {};

  const int s0 = wid, s1 = wid + 4;       // 1KB segments this wave stages
  const int oA0 = s0 * 1024 + lane * 16;  // linear byte offset in 8KB tile
  const int oA1 = s1 * 1024 + lane * 16;

  const char* gA0 = (const char*)A + (((size_t)(brow + (oA0 >> 6)) * lda) << 1) + (oA0 & 63);
  const char* gA1 = (const char*)A + (((size_t)(brow + (oA1 >> 6)) * lda) << 1) + (oA1 & 63);
  const char* gB0 = (const char*)Bt + (((size_t)(bcol + (oA0 >> 6)) * ldb) << 1) + (oA0 & 63);
  const char* gB1 = (const char*)Bt + (((size_t)(bcol + (oA1 >> 6)) * ldb) << 1) + (oA1 & 63);

#define STAGE(buf, koff)                                              \
  {                                                                   \
    gload_lds16(gA0 + (koff), (char*)As + (buf) * 8192 + s0 * 1024);  \
    gload_lds16(gA1 + (koff), (char*)As + (buf) * 8192 + s1 * 1024);  \
    gload_lds16(gB0 + (koff), (char*)Bs + (buf) * 8192 + s0 * 1024);  \
    gload_lds16(gB1 + (koff), (char*)Bs + (buf) * 8192 + s1 * 1024);  \
  }

  const int nk = K >> 5;
  STAGE(0, 0);
  __syncthreads();
  int cur = 0;
  for (int kt = 0; kt < nk; ++kt) {
    const int koff = (kt + 1 < nk ? kt + 1 : kt) << 6;
    STAGE(cur ^ 1, koff);  // prefetch next tile; flight overlaps compute

    const char* Ab = (const char*)As + cur * 8192;
    const char* Bb = (const char*)Bs + cur * 8192;
    bf16x8 af[4], bfr[4];
#pragma unroll
    for (int m = 0; m < 4; ++m) {
      int r = wr * 64 + m * 16 + (lane & 15);
      af[m] = *(const bf16x8*)(Ab + r * 64 + ((lane >> 4) << 4));
    }
#pragma unroll
    for (int n = 0; n < 4; ++n) {
      int cidx = wc * 64 + n * 16 + (lane & 15);
      bfr[n] = *(const bf16x8*)(Bb + cidx * 64 + ((lane >> 4) << 4));
    }
#pragma unroll
    for (int m = 0; m < 4; ++m)
#pragma unroll
      for (int n = 0; n < 4; ++n)
        acc[m][n] = __builtin_amdgcn_mfma_f32_16x16x32_bf16(af[m], bfr[n], acc[m][n], 0, 0, 0);

    __syncthreads();
    cur ^= 1;
  }
#undef STAGE

  float* __restrict__ C = gg.C[g];
  u16* __restrict__ Cb = gg.Cb[g];
  const float* __restrict__ bias = gg.bias[g];
  const float* __restrict__ aux = gg.aux[g];
  const int ldc = gg.ldc[g];
  const int ldcb = gg.ldcb[g];
  const int epi = gg.epi[g];

  const int r0 = brow + wr * 64 + ((lane >> 4) << 2);
  const int c0 = bcol + wc * 64 + (lane & 15);
#pragma unroll
  for (int m = 0; m < 4; ++m) {
#pragma unroll
    for (int n = 0; n < 4; ++n) {
#pragma unroll
      for (int j = 0; j < 4; ++j) {
        int gr = r0 + m * 16 + j;
        int gc = c0 + n * 16;
        float v = acc[m][n][j];
        if (epi == EPI_F32) {
          C[(size_t)gr * ldc + gc] = v;
        } else if (epi == EPI_BF16) {
          Cb[(size_t)gr * ldcb + gc] = bf16_bits(v);
        } else {  // EPI_DHALF: 0.5*ctm*sigmoid(v + bias)
          size_t ci = (size_t)gr * ldc + gc;
          C[ci] = 0.5f * aux[ci] * sigm(v + bias[gc]);
        }
      }
    }
  }
}

// ---------- softmax + x + crohis blend ----------
// TP0/TP1: t12|t21 split-K partials (f32, ld 2048). TV_B: v12|v21 (bf16, ld 2048).
// DCRO = 0.5*ctm*sigmoid(decomp) from G1.
// block = (row, half): t = TP0+TP1; s = tanh(t)*v; ca = softmax(s);
// x = e*ca; cro = DCRO + 0.5*x
__global__ __launch_bounds__(256) void softmax_cro_kernel(
    const float* __restrict__ TP0, const float* __restrict__ TP1,
    const u16* __restrict__ TV_B, const float* __restrict__ DCRO,
    const u16* __restrict__ E_B, u16* __restrict__ XH_B,
    float* __restrict__ out_cro, u16* __restrict__ CRO_B) {
  __shared__ float smx[4], sms[4];
  int row = blockIdx.x >> 1;
  int half = blockIdx.x & 1;
  size_t base = (size_t)row * 2048 + half * 1024;
  int tid = threadIdx.x;
  float s[4];
  float lmax = -1e30f;
#pragma unroll
  for (int i = 0; i < 4; ++i) {
    int c = tid + (i << 8);
    float t = TP0[base + c] + TP1[base + c];
    s[i] = tanhf(t) * bits_f32(TV_B[base + c]);
    lmax = fmaxf(lmax, s[i]);
  }
#pragma unroll
  for (int o = 32; o; o >>= 1) lmax = fmaxf(lmax, __shfl_xor(lmax, o, 64));
  if ((tid & 63) == 0) smx[tid >> 6] = lmax;
  __syncthreads();
  float bmax = fmaxf(fmaxf(smx[0], smx[1]), fmaxf(smx[2], smx[3]));
  float lsum = 0.f;
#pragma unroll
  for (int i = 0; i < 4; ++i) { s[i] = expf(s[i] - bmax); lsum += s[i]; }
#pragma unroll
  for (int o = 32; o; o >>= 1) lsum += __shfl_xor(lsum, o, 64);
  if ((tid & 63) == 0) sms[tid >> 6] = lsum;
  __syncthreads();
  float inv = 1.f / (sms[0] + sms[1] + sms[2] + sms[3]);
#pragma unroll
  for (int i = 0; i < 4; ++i) {
    int c = tid + (i << 8);
    int col = half * 1024 + c;
    size_t mi = (size_t)row * 2048 + col;
    float x = bits_f32(E_B[mi]) * s[i] * inv;
    XH_B[(size_t)row * 3072 + col] = bf16_bits(x);
    float cro = DCRO[mi] + 0.5f * x;
    out_cro[mi] = cro;
    CRO_B[mi] = bf16_bits(cro);
  }
}

// ---------- LSTM gates (fuses z and h_cro split-K combines) ----------
__global__ __launch_bounds__(256) void gates_kernel(
    const float* __restrict__ ZP0, const float* __restrict__ ZP1,
    const float* __restrict__ bias, const float* __restrict__ c_tm1,
    const float* __restrict__ HP0, const float* __restrict__ HP1,
    const float* __restrict__ b_cro, float* __restrict__ out_h,
    float* __restrict__ out_c) {
  int i = blockIdx.x * 256 + threadIdx.x;  // 0..524287, 4 units each
  int row = i >> 8;
  int u0 = (i & 255) << 2;
  size_t zb = (size_t)row * 4096;
  f32x4 zi = *(const f32x4*)(ZP0 + zb + u0);
  f32x4 zf = *(const f32x4*)(ZP0 + zb + 1024 + u0);
  f32x4 zc = *(const f32x4*)(ZP0 + zb + 2048 + u0);
  f32x4 zo = *(const f32x4*)(ZP0 + zb + 3072 + u0);
  f32x4 yi = *(const f32x4*)(ZP1 + zb + u0);
  f32x4 yf = *(const f32x4*)(ZP1 + zb + 1024 + u0);
  f32x4 yc = *(const f32x4*)(ZP1 + zb + 2048 + u0);
  f32x4 yo = *(const f32x4*)(ZP1 + zb + 3072 + u0);
  f32x4 bi = *(const f32x4*)(bias + u0);
  f32x4 bff = *(const f32x4*)(bias + 1024 + u0);
  f32x4 bc = *(const f32x4*)(bias + 2048 + u0);
  f32x4 bo = *(const f32x4*)(bias + 3072 + u0);
  size_t hb = (size_t)row * 1024 + u0;
  f32x4 ct = *(const f32x4*)(c_tm1 + hb);
  f32x4 h0 = *(const f32x4*)(HP0 + hb);
  f32x4 h1 = *(const f32x4*)(HP1 + hb);
  f32x4 bcr = *(const f32x4*)(b_cro + u0);
  f32x4 h, c;
#pragma unroll
  for (int k = 0; k < 4; ++k) {
    float I = sigm(zi[k] + yi[k] + bi[k]);
    float F = sigm(zf[k] + yf[k] + bff[k]);
    float O = sigm(zo[k] + yo[k] + bo[k]);
    float cc = F * ct[k] + I * tanhf(zc[k] + yc[k] + bc[k]);
    float hcro = tanhf(h0[k] + h1[k] + bcr[k]);
    c[k] = cc;
    h[k] = O * tanhf(cc) + hcro;
  }
  *(f32x4*)(out_h + (size_t)row * 1024 + u0) = h;
  *(f32x4*)(out_c + (size_t)row * 1024 + u0) = c;
}

// ---------- launch ----------
extern "C" void kernel_launch(void* const* d_in, const int* in_sizes, int n_in,
                              void* d_out, int out_size, void* d_ws, size_t ws_size,
                              hipStream_t stream) {
  const float* in_inputs = (const float*)d_in[0];
  const float* in_h      = (const float*)d_in[1];
  const float* in_c      = (const float*)d_in[2];
  const float* in_ctm    = (const float*)d_in[3];
  const float* w_e1      = (const float*)d_in[4];
  const float* w_e2      = (const float*)d_in[5];
  const float* w12w      = (const float*)d_in[6];
  const float* w12u      = (const float*)d_in[7];
  const float* w12v      = (const float*)d_in[8];
  const float* w21w      = (const float*)d_in[9];
  const float* w21u      = (const float*)d_in[10];
  const float* w21v      = (const float*)d_in[11];
  const float* w_cro     = (const float*)d_in[12];
  const float* b_cro     = (const float*)d_in[13];
  const float* w_dec     = (const float*)d_in[14];
  const float* b_dec     = (const float*)d_in[15];
  const float* w_k       = (const float*)d_in[16];
  const float* w_rk      = (const float*)d_in[17];
  const float* b_z       = (const float*)d_in[18];

  float* out_h   = (float*)d_out;
  float* out_c   = out_h + (size_t)2048 * 1024;
  float* out_cro = out_h + (size_t)2 * 2048 * 1024;

  // Workspace layout (164 MiB total, matching the largest measured-good
  // footprint). All sizes are 256B multiples; phase-B split-K partials alias
  // phase-A buffers that are dead by G3:
  //   ZP0 (32MB) <- [BF_IN | BF_CROTM | E_B]   (dead after G1/softmax)
  //   ZP1 (32MB) <- [TP0 | TP1]                (dead after softmax)
  //   HP0 ( 8MB) <- TV_B                       (dead after softmax)
  //   HP1 ( 8MB) <- DCRO (first half)          (dead after softmax)
  char* ws = (char*)d_ws;
  size_t off = 0;
  auto alloc = [&](size_t bytes) {
    char* p = ws + off;
    off += (bytes + 255) & ~(size_t)255;
    return p;
  };
  u16* BF_IN    = (u16*)alloc((size_t)2048 * 4096 * 2);   // 16MB bf16 inputs
  u16* BF_CROTM = (u16*)alloc((size_t)2048 * 2048 * 2);   //  8MB bf16 crohis_tm
  u16* E_B      = (u16*)alloc((size_t)2048 * 2048 * 2);   //  8MB [e1|e2] bf16
  u16* XH_B     = (u16*)alloc((size_t)2048 * 3072 * 2);   // 12MB [x|h] bf16
  u16* CRO_B    = (u16*)alloc((size_t)2048 * 2048 * 2);   //  8MB bf16 new crohis
  u16* WT_E1    = (u16*)alloc((size_t)1024 * 2048 * 2);   //  4MB
  u16* WT_E2    = (u16*)alloc((size_t)1024 * 2048 * 2);   //  4MB
  u16* WT_T     = (u16*)alloc((size_t)2048 * 2048 * 2);   //  8MB [t12|t21] x K
  u16* WT_V12   = (u16*)alloc((size_t)1024 * 1024 * 2);   //  2MB
  u16* WT_V21   = (u16*)alloc((size_t)1024 * 1024 * 2);   //  2MB
  u16* WT_CRO   = (u16*)alloc((size_t)1024 * 2048 * 2);   //  4MB
  u16* WT_DEC   = (u16*)alloc((size_t)2048 * 2048 * 2);   //  8MB
  u16* WT_KRK   = (u16*)alloc((size_t)4096 * 3072 * 2);   // 24MB [kernel;rk]
  float* TP0    = (float*)alloc((size_t)2048 * 2048 * 4); // 16MB t partial k0
  float* TP1    = (float*)alloc((size_t)2048 * 2048 * 4); // 16MB t partial k1
  u16* TV_B     = (u16*)alloc((size_t)2048 * 2048 * 2);   //  8MB [v12|v21] bf16
  float* DCRO   = (float*)alloc((size_t)2048 * 2048 * 4); // 16MB 0.5*ctm*sig(d)
  // phase-B aliases (no new allocations)
  float* ZP0 = (float*)ws;        // 32MB over BF_IN+BF_CROTM+E_B
  float* ZP1 = TP0;               // 32MB over TP0+TP1
  float* HP0 = (float*)TV_B;      //  8MB over TV_B
  float* HP1 = DCRO;              //  8MB over DCRO[0:2M]

  // 1) fused conversions
  cvt_all_kernel<<<7168, 256, 0, stream>>>(in_inputs, in_ctm, in_h, BF_IN, BF_CROTM, XH_B);

  // 2) grouped weight transposes
  {
    TransGroups tg;
    int s = 0, gi = 0;
    auto add = [&](const float* src, int K, int N, u16* dst, int ld, long long dOff) {
      tg.src[gi] = src; tg.dst[gi] = dst; tg.N[gi] = N; tg.ld[gi] = ld; tg.off[gi] = dOff;
      tg.start[gi] = s; s += (K >> 6) * (N >> 5); ++gi;
    };
    add(w_e1, 2048, 1024, WT_E1, 2048, 0);
    add(w_e2, 2048, 1024, WT_E2, 2048, 0);
    add(w12w, 1024, 1024, WT_T, 2048, 0);
    add(w12u, 1024, 1024, WT_T, 2048, 1024);
    add(w21u, 1024, 1024, WT_T, 2048, (long long)1024 * 2048);
    add(w21w, 1024, 1024, WT_T, 2048, (long long)1024 * 2048 + 1024);
    add(w12v, 1024, 1024, WT_V12, 1024, 0);
    add(w21v, 1024, 1024, WT_V21, 1024, 0);
    add(w_cro, 2048, 1024, WT_CRO, 2048, 0);
    add(w_dec, 2048, 2048, WT_DEC, 2048, 0);
    add(w_k, 2048, 4096, WT_KRK, 3072, 0);
    add(w_rk, 1024, 4096, WT_KRK, 3072, 2048);
    tg.start[12] = s;
    transpose_all_kernel<<<s, 256, 0, stream>>>(tg);
  }

  auto mkgrp = [&]() {
    GemmGroups gg;
    for (int i = 0; i < 4; ++i) {
      gg.A[i] = nullptr; gg.Bt[i] = nullptr; gg.C[i] = nullptr; gg.Cb[i] = nullptr;
      gg.bias[i] = nullptr; gg.aux[i] = nullptr;
      gg.lda[i] = 0; gg.ldb[i] = 32; gg.K[i] = 32; gg.nbx[i] = 1;
      gg.ldc[i] = 0; gg.ldcb[i] = 0; gg.epi[i] = EPI_F32; gg.start[i] = 0x7fffffff;
    }
    return gg;
  };

  // 3) G1: decomp(256, K=2048, DHALF) | e1(128) | e2(128) -> 512 blocks
  {
    GemmGroups gg = mkgrp();
    gg.A[0] = BF_CROTM; gg.Bt[0] = WT_DEC; gg.lda[0] = 2048; gg.ldb[0] = 2048;
    gg.K[0] = 2048; gg.nbx[0] = 16; gg.C[0] = DCRO; gg.ldc[0] = 2048;
    gg.epi[0] = EPI_DHALF; gg.bias[0] = b_dec; gg.aux[0] = in_ctm; gg.start[0] = 0;
    gg.A[1] = BF_IN; gg.Bt[1] = WT_E1; gg.lda[1] = 4096; gg.ldb[1] = 2048;
    gg.K[1] = 2048; gg.nbx[1] = 8; gg.Cb[1] = E_B; gg.ldcb[1] = 2048;
    gg.epi[1] = EPI_BF16; gg.start[1] = 256;
    gg.A[2] = BF_IN + 2048; gg.Bt[2] = WT_E2; gg.lda[2] = 4096; gg.ldb[2] = 2048;
    gg.K[2] = 2048; gg.nbx[2] = 8; gg.Cb[2] = E_B + 1024; gg.ldcb[2] = 2048;
    gg.epi[2] = EPI_BF16; gg.start[2] = 384;
    gemm_grouped<<<512, 256, 0, stream>>>(gg);
  }

  // 4) G2: t-k0(256) | t-k1(256) | v12(128,bf16) | v21(128,bf16) -> 768 blocks
  {
    GemmGroups gg = mkgrp();
    gg.A[0] = E_B; gg.Bt[0] = WT_T; gg.lda[0] = 2048; gg.ldb[0] = 2048;
    gg.K[0] = 1024; gg.nbx[0] = 16; gg.C[0] = TP0; gg.ldc[0] = 2048;
    gg.epi[0] = EPI_F32; gg.start[0] = 0;
    gg.A[1] = E_B + 1024; gg.Bt[1] = WT_T + 1024; gg.lda[1] = 2048; gg.ldb[1] = 2048;
    gg.K[1] = 1024; gg.nbx[1] = 16; gg.C[1] = TP1; gg.ldc[1] = 2048;
    gg.epi[1] = EPI_F32; gg.start[1] = 256;
    gg.A[2] = E_B + 1024; gg.Bt[2] = WT_V12; gg.lda[2] = 2048; gg.ldb[2] = 1024;
    gg.K[2] = 1024; gg.nbx[2] = 8; gg.Cb[2] = TV_B; gg.ldcb[2] = 2048;
    gg.epi[2] = EPI_BF16; gg.start[2] = 512;
    gg.A[3] = E_B; gg.Bt[3] = WT_V21; gg.lda[3] = 2048; gg.ldb[3] = 1024;
    gg.K[3] = 1024; gg.nbx[3] = 8; gg.Cb[3] = TV_B + 1024; gg.ldcb[3] = 2048;
    gg.epi[3] = EPI_BF16; gg.start[3] = 640;
    gemm_grouped<<<768, 256, 0, stream>>>(gg);
  }

  // 5) softmax + x + crohis blend
  softmax_cro_kernel<<<4096, 256, 0, stream>>>(TP0, TP1, TV_B, DCRO, E_B,
                                               XH_B, out_cro, CRO_B);

  // 6) G3: z-k0(512) | z-k1(512) | hcro-k0(128) | hcro-k1(128) -> 1280 blocks
  {
    GemmGroups gg = mkgrp();
    gg.A[0] = XH_B; gg.Bt[0] = WT_KRK; gg.lda[0] = 3072; gg.ldb[0] = 3072;
    gg.K[0] = 1536; gg.nbx[0] = 32; gg.C[0] = ZP0; gg.ldc[0] = 4096;
    gg.epi[0] = EPI_F32; gg.start[0] = 0;
    gg.A[1] = XH_B + 1536; gg.Bt[1] = WT_KRK + 1536; gg.lda[1] = 3072; gg.ldb[1] = 3072;
    gg.K[1] = 1536; gg.nbx[1] = 32; gg.C[1] = ZP1; gg.ldc[1] = 4096;
    gg.epi[1] = EPI_F32; gg.start[1] = 512;
    gg.A[2] = CRO_B; gg.Bt[2] = WT_CRO; gg.lda[2] = 2048; gg.ldb[2] = 2048;
    gg.K[2] = 1024; gg.nbx[2] = 8; gg.C[2] = HP0; gg.ldc[2] = 1024;
    gg.epi[2] = EPI_F32; gg.start[2] = 1024;
    gg.A[3] = CRO_B + 1024; gg.Bt[3] = WT_CRO + 1024; gg.lda[3] = 2048; gg.ldb[3] = 2048;
    gg.K[3] = 1024; gg.nbx[3] = 8; gg.C[3] = HP1; gg.ldc[3] = 1024;
    gg.epi[3] = EPI_F32; gg.start[3] = 1152;
    gemm_grouped<<<1280, 256, 0, stream>>>(gg);
  }

  // 7) gates -> h, c (fuses z and h_cro combines)
  gates_kernel<<<2048, 256, 0, stream>>>(ZP0, ZP1, b_z, in_c, HP0, HP1, b_cro,
                                         out_h, out_c);
}